// Round 4
// baseline (234.435 us; speedup 1.0000x reference)
//
#include <hip/hip_runtime.h>
#include <stdint.h>

#define SIZE 65535

typedef __bf16 bf16x8 __attribute__((ext_vector_type(8)));
typedef float floatx4 __attribute__((ext_vector_type(4)));

// ws layout (bf16 elements), FRAGMENT-LINEAR: chunk = tile*64 + lane, 8 elems/chunk.
#define WS_ENCW 0        // [nt8][kt8][lane][8]        -> 32768
#define WS_WIH  32768    // [nt8][g3][kt4][lane][8]    -> 49152
#define WS_WHH  81920    // [nt8][g3][kt4][lane][8]    -> 49152
#define WS_VW   131072   // [nt4][kt4][lane][8]        -> 8192
#define WS_DECW 139264   // [kt8][lane][8] (rows>=10 and kt>=6 zero) -> 4096
#define WS_TOTC 17920    // weight chunks (x8 elems = 143360 shorts)
#define X_WS    143360   // x intermediate, bf16 row-major [65536][128] -> 8388608 shorts
// total ws usage: (143360 + 65536*128)*2 B = 17.06 MB

__device__ __forceinline__ unsigned short f2bf(float f) {
    union { float f; unsigned int u; } v; v.f = f;
    unsigned int u = v.u;
    return (unsigned short)((u + 0x7fffu + ((u >> 16) & 1u)) >> 16);
}
__device__ __forceinline__ float sigmf(float x) {
    x = fminf(fmaxf(x, -30.f), 30.f);
    return 1.f / (1.f + __expf(-x));
}
__device__ __forceinline__ float tanhfast(float x) {
    x = fminf(fmaxf(x, -15.f), 15.f);
    float e = __expf(2.f * x);
    return (e - 1.f) / (e + 1.f);
}

union BF8 { bf16x8 v; unsigned short s[8]; };

__device__ __forceinline__ bf16x8 cvt8g(const float* p) {
    float4 a = *reinterpret_cast<const float4*>(p);
    float4 b = *reinterpret_cast<const float4*>(p + 4);
    BF8 r;
    r.s[0] = f2bf(a.x); r.s[1] = f2bf(a.y); r.s[2] = f2bf(a.z); r.s[3] = f2bf(a.w);
    r.s[4] = f2bf(b.x); r.s[5] = f2bf(b.y); r.s[6] = f2bf(b.z); r.s[7] = f2bf(b.w);
    return r.v;
}
__device__ __forceinline__ bf16x8 ld8(const unsigned short* p) {
    return *reinterpret_cast<const bf16x8*>(p);
}
// async global->LDS, 16B/lane; LDS dest = wave-uniform base + lane*16 (our
// per-thread dst pointers are lane-consecutive by construction).
__device__ __forceinline__ void glds16(const unsigned short* g, unsigned short* l) {
    __builtin_amdgcn_global_load_lds(
        (const __attribute__((address_space(1))) unsigned int*)g,
        (__attribute__((address_space(3))) unsigned int*)l, 16, 0, 0);
}

// ---------- pre-kernel: f32 weights -> bf16 fragment-linear layout ----------
__global__ __launch_bounds__(256) void cvt_weights(
    const float* __restrict__ enc_w, const float* __restrict__ w_ih,
    const float* __restrict__ w_hh, const float* __restrict__ v_w,
    const float* __restrict__ dec_w, unsigned short* __restrict__ ws) {
    int c = blockIdx.x * 256 + threadIdx.x;
    if (c >= WS_TOTC) return;
    const int lane = c & 63;
    const int l = lane & 15;
    const int q = lane >> 4;
    const float* src; int row, col, stride; bool zero = false;
    if (c < 4096) {                      // enc_w [nt8][kt8]
        int lt = c >> 6; int nt = lt >> 3, kt = lt & 7;
        row = nt * 16 + l; col = kt * 32 + q * 8; src = enc_w; stride = 256;
    } else if (c < 10240) {              // w_ih [nt8][g3][kt4]
        int lt = (c - 4096) >> 6; int nt = lt / 12; int r2 = lt % 12;
        int g = r2 >> 2, kt = r2 & 3;
        row = g * 128 + nt * 16 + l; col = kt * 32 + q * 8; src = w_ih; stride = 128;
    } else if (c < 16384) {              // w_hh
        int lt = (c - 10240) >> 6; int nt = lt / 12; int r2 = lt % 12;
        int g = r2 >> 2, kt = r2 & 3;
        row = g * 128 + nt * 16 + l; col = kt * 32 + q * 8; src = w_hh; stride = 128;
    } else if (c < 17408) {              // v_w [nt4][kt4]
        int lt = (c - 16384) >> 6; int nt = lt >> 2, kt = lt & 3;
        row = nt * 16 + l; col = kt * 32 + q * 8; src = v_w; stride = 128;
    } else {                             // dec_w [kt8], zero rows>=10 / kt>=6
        int kt = (c - 17408) >> 6;
        row = l; col = kt * 32 + q * 8; src = dec_w; stride = 192;
        zero = (l >= 10) || (kt >= 6);
    }
    float4 a, b;
    if (zero) { a = make_float4(0.f,0.f,0.f,0.f); b = a; }
    else {
        const float* p = src + (size_t)row * stride + col;
        a = *reinterpret_cast<const float4*>(p);
        b = *reinterpret_cast<const float4*>(p + 4);
    }
    unsigned short* d = ws + (size_t)c * 8;
    d[0]=f2bf(a.x); d[1]=f2bf(a.y); d[2]=f2bf(a.z); d[3]=f2bf(a.w);
    d[4]=f2bf(b.x); d[5]=f2bf(b.y); d[6]=f2bf(b.z); d[7]=f2bf(b.w);
}

// ---------- pass 1: X = relu(OBS @ enc_w^T + enc_b) -> x bf16 in ws ----------
// SWAPPED operands: mfma(a=W_frag, b=obs_frag) gives D[outcol][row] so each
// thread holds 4 CONSECUTIVE outcols for one row -> direct ushort4 store of x,
// no LDS transpose buffer. LDS = enc_w 64KB only -> weights staged once/block,
// then pure HBM streaming. 2 blocks/CU.
__global__ __launch_bounds__(256, 2) void pass1_enc(
    const float* __restrict__ obs,    // [SIZE,256] f32
    const float* __restrict__ enc_b,  // [128] f32
    const unsigned short* __restrict__ wsw,
    unsigned short* __restrict__ xws) // x bf16 [65536][128]
{
    __shared__ __align__(16) unsigned short wenc[32768];   // 64 KB

    const int tid  = threadIdx.x;
    const int wave = tid >> 6;
    const int lane = tid & 63;
    const int l15  = lane & 15;
    const int quad = lane >> 4;
    const int wrow0 = blockIdx.x * 128 + wave * 32;

    // stage enc_w (4096 lane-chunks, 16 per thread), async
#pragma unroll
    for (int s = 0; s < 16; ++s) {
        const int c = s * 256 + tid;
        glds16(wsw + WS_ENCW + (size_t)c * 8, wenc + (size_t)c * 8);
    }

    int rA0 = wrow0 + l15;      rA0 = (rA0 < SIZE) ? rA0 : (SIZE - 1);
    int rA1 = wrow0 + 16 + l15; rA1 = (rA1 < SIZE) ? rA1 : (SIZE - 1);

    // obs B-fragments (row=l15, k=quad*8..): same lane map as A-frags
    bf16x8 bo[2][8];
    {
        const float* o0 = obs + (size_t)rA0 * 256;
        const float* o1 = obs + (size_t)rA1 * 256;
#pragma unroll
        for (int kt = 0; kt < 8; ++kt) {
            bo[0][kt] = cvt8g(o0 + kt * 32 + quad * 8);
            bo[1][kt] = cvt8g(o1 + kt * 32 + quad * 8);
        }
    }
    __syncthreads();   // staging + own loads drained

#pragma unroll 1
    for (int nt = 0; nt < 8; ++nt) {
        floatx4 d0 = floatx4{0.f,0.f,0.f,0.f}, d1 = d0;
#pragma unroll
        for (int kt = 0; kt < 8; ++kt) {
            bf16x8 a = ld8(&wenc[(nt * 8 + kt) * 512 + lane * 8]);
            d0 = __builtin_amdgcn_mfma_f32_16x16x32_bf16(a, bo[0][kt], d0, 0, 0, 0);
            d1 = __builtin_amdgcn_mfma_f32_16x16x32_bf16(a, bo[1][kt], d1, 0, 0, 0);
        }
        const float4 ebv = *reinterpret_cast<const float4*>(enc_b + nt * 16 + quad * 4);
        const float eb[4] = {ebv.x, ebv.y, ebv.z, ebv.w};
#pragma unroll
        for (int m = 0; m < 2; ++m) {
            const int grow = wrow0 + m * 16 + l15;
            if (grow < SIZE) {
                const floatx4& d = m ? d1 : d0;
                ushort4 pk;
                pk.x = f2bf(fmaxf(d[0] + eb[0], 0.f));
                pk.y = f2bf(fmaxf(d[1] + eb[1], 0.f));
                pk.z = f2bf(fmaxf(d[2] + eb[2], 0.f));
                pk.w = f2bf(fmaxf(d[3] + eb[3], 0.f));
                *reinterpret_cast<ushort4*>(xws + (size_t)grow * 128 + nt * 16 + quad * 4) = pk;
            }
        }
    }
}

// ---------- pass 2: GRU cell -> h_out f32 (final output region) ----------
// Col-quarter split: block q handles out-cols 32q..32q+32 -> w_ih/w_hh quarter
// slices = 48KB LDS, 3 blocks/CU. Swapped operands again: direct float4 h
// stores. x read as bf16 fragments straight from ws (no cvt); hid cvt'd.
// Adjacent blockIdx = same rows, different quarter -> x/hid L2/L3 reuse.
__global__ __launch_bounds__(256, 3) void pass2_gru(
    const float* __restrict__ hid,    // [SIZE,128] f32
    const float* __restrict__ b_ih,   // [384] f32
    const float* __restrict__ b_hh,   // [384] f32
    const unsigned short* __restrict__ wsw,
    const unsigned short* __restrict__ xws,
    float* __restrict__ out_h)        // [SIZE,128] f32
{
    __shared__ __align__(16) unsigned short wq[24576];   // 48 KB: [ih|hh] x [2ntL][3g][4kt]

    const int tid  = threadIdx.x;
    const int wave = tid >> 6;
    const int lane = tid & 63;
    const int l15  = lane & 15;
    const int quad = lane >> 4;
    const int q    = blockIdx.x & 3;
    const int tile = blockIdx.x >> 2;
    const int wrow0 = tile * 128 + wave * 32;

    // stage 48 frag-slots (3072 lane-chunks, 12 per thread)
#pragma unroll
    for (int s = 0; s < 12; ++s) {
        const int c = s * 256 + tid;          // 0..3071
        const int f = c >> 6, li = c & 63;
        int ff = (f < 24) ? f : f - 24;
        const int ntL = ff / 12, rm = ff % 12;
        const int g = rm >> 2, kt = rm & 3;
        const int gidx = (((q * 2 + ntL) * 3 + g) * 4 + kt);
        const unsigned short* src = wsw + ((f < 24) ? WS_WIH : WS_WHH)
                                        + (size_t)gidx * 512 + li * 8;
        glds16(src, wq + (size_t)c * 8);
    }

    int rA0 = wrow0 + l15;      rA0 = (rA0 < SIZE) ? rA0 : (SIZE - 1);
    int rA1 = wrow0 + 16 + l15; rA1 = (rA1 < SIZE) ? rA1 : (SIZE - 1);

    bf16x8 xb[2][4], hb[2][4];
#pragma unroll
    for (int kt = 0; kt < 4; ++kt) {
        xb[0][kt] = ld8(xws + (size_t)rA0 * 128 + kt * 32 + quad * 8);
        xb[1][kt] = ld8(xws + (size_t)rA1 * 128 + kt * 32 + quad * 8);
        hb[0][kt] = cvt8g(hid + (size_t)rA0 * 128 + kt * 32 + quad * 8);
        hb[1][kt] = cvt8g(hid + (size_t)rA1 * 128 + kt * 32 + quad * 8);
    }
    __syncthreads();

#pragma unroll 1
    for (int ntL = 0; ntL < 2; ++ntL) {
        const int oc0 = q * 32 + ntL * 16;
        floatx4 gi[3][2], gh[3][2];
#pragma unroll
        for (int g = 0; g < 3; ++g) {
            gi[g][0] = floatx4{0.f,0.f,0.f,0.f}; gi[g][1] = gi[g][0];
            gh[g][0] = gi[g][0]; gh[g][1] = gi[g][0];
        }
#pragma unroll
        for (int g = 0; g < 3; ++g)
#pragma unroll
            for (int kt = 0; kt < 4; ++kt) {
                bf16x8 ai = ld8(&wq[((ntL * 3 + g) * 4 + kt) * 512 + lane * 8]);
                bf16x8 ah = ld8(&wq[12288 + ((ntL * 3 + g) * 4 + kt) * 512 + lane * 8]);
                gi[g][0] = __builtin_amdgcn_mfma_f32_16x16x32_bf16(ai, xb[0][kt], gi[g][0], 0, 0, 0);
                gi[g][1] = __builtin_amdgcn_mfma_f32_16x16x32_bf16(ai, xb[1][kt], gi[g][1], 0, 0, 0);
                gh[g][0] = __builtin_amdgcn_mfma_f32_16x16x32_bf16(ah, hb[0][kt], gh[g][0], 0, 0, 0);
                gh[g][1] = __builtin_amdgcn_mfma_f32_16x16x32_bf16(ah, hb[1][kt], gh[g][1], 0, 0, 0);
            }
        // epilogue loads (L2-hot), after MFMA to keep live-range small
        const float4 birv = *reinterpret_cast<const float4*>(b_ih + oc0 + quad * 4);
        const float4 bizv = *reinterpret_cast<const float4*>(b_ih + 128 + oc0 + quad * 4);
        const float4 binv = *reinterpret_cast<const float4*>(b_ih + 256 + oc0 + quad * 4);
        const float4 bhrv = *reinterpret_cast<const float4*>(b_hh + oc0 + quad * 4);
        const float4 bhzv = *reinterpret_cast<const float4*>(b_hh + 128 + oc0 + quad * 4);
        const float4 bhnv = *reinterpret_cast<const float4*>(b_hh + 256 + oc0 + quad * 4);
        const float bir[4] = {birv.x, birv.y, birv.z, birv.w};
        const float biz[4] = {bizv.x, bizv.y, bizv.z, bizv.w};
        const float bin[4] = {binv.x, binv.y, binv.z, binv.w};
        const float bhr[4] = {bhrv.x, bhrv.y, bhrv.z, bhrv.w};
        const float bhz[4] = {bhzv.x, bhzv.y, bhzv.z, bhzv.w};
        const float bhn[4] = {bhnv.x, bhnv.y, bhnv.z, bhnv.w};
#pragma unroll
        for (int m = 0; m < 2; ++m) {
            const int grow = wrow0 + m * 16 + l15;
            const int rowc = (grow < SIZE) ? grow : (SIZE - 1);
            const float4 hpv = *reinterpret_cast<const float4*>(hid + (size_t)rowc * 128 + oc0 + quad * 4);
            const float hp[4] = {hpv.x, hpv.y, hpv.z, hpv.w};
            float ho[4];
#pragma unroll
            for (int r = 0; r < 4; ++r) {
                float rg = sigmf(gi[0][m][r] + bir[r] + gh[0][m][r] + bhr[r]);
                float zg = sigmf(gi[1][m][r] + biz[r] + gh[1][m][r] + bhz[r]);
                float ng = tanhfast(gi[2][m][r] + bin[r] + rg * (gh[2][m][r] + bhn[r]));
                ho[r] = (1.f - zg) * ng + zg * hp[r];
            }
            if (grow < SIZE)
                *reinterpret_cast<float4*>(out_h + (size_t)grow * 128 + oc0 + quad * 4) =
                    make_float4(ho[0], ho[1], ho[2], ho[3]);
        }
    }
}

// ---------- pass 3: V = relu(H@v_w^T+v_b); OUT = [H|V]@dec_w^T + dec_b ----------
// Unswapped (data rows = M) since dec consumes v as A-side: small per-wave sV
// transpose buffer. Weights 24KB resident; 3 blocks/CU.
__global__ __launch_bounds__(256, 3) void pass3_vdec(
    const float* __restrict__ hsrc,   // out_h [SIZE,128] f32 (from pass 2)
    const float* __restrict__ v_b,    // [64] f32
    const float* __restrict__ dec_b,  // [10] f32
    const unsigned short* __restrict__ wsw,
    float* __restrict__ out)          // [SIZE*10] f32
{
    __shared__ __align__(16) unsigned short wv[8192];    // 16 KB [4nt][4kt]
    __shared__ __align__(16) unsigned short wdec[4096];  // 8 KB [8kt] (6 used)
    __shared__ __align__(16) unsigned short sV[4][32][72];
    __shared__ __align__(16) float sO[4][32][10];

    const int tid  = threadIdx.x;
    const int wave = tid >> 6;
    const int lane = tid & 63;
    const int l15  = lane & 15;
    const int quad = lane >> 4;
    const int wrow0 = blockIdx.x * 128 + wave * 32;

#pragma unroll
    for (int s = 0; s < 4; ++s) {
        const int c = s * 256 + tid;          // 0..1023
        glds16(wsw + WS_VW + (size_t)c * 8, wv + (size_t)c * 8);
    }
#pragma unroll
    for (int s = 0; s < 2; ++s) {
        const int c = s * 256 + tid;          // 0..511
        glds16(wsw + WS_DECW + (size_t)c * 8, wdec + (size_t)c * 8);
    }

    int rA0 = wrow0 + l15;      rA0 = (rA0 < SIZE) ? rA0 : (SIZE - 1);
    int rA1 = wrow0 + 16 + l15; rA1 = (rA1 < SIZE) ? rA1 : (SIZE - 1);

    bf16x8 ha[2][4];
#pragma unroll
    for (int kt = 0; kt < 4; ++kt) {
        ha[0][kt] = cvt8g(hsrc + (size_t)rA0 * 128 + kt * 32 + quad * 8);
        ha[1][kt] = cvt8g(hsrc + (size_t)rA1 * 128 + kt * 32 + quad * 8);
    }
    __syncthreads();

    // V
#pragma unroll 1
    for (int nt = 0; nt < 4; ++nt) {
        floatx4 a0 = floatx4{0.f,0.f,0.f,0.f}, a1 = a0;
#pragma unroll
        for (int kt = 0; kt < 4; ++kt) {
            bf16x8 b = ld8(&wv[(nt * 4 + kt) * 512 + lane * 8]);
            a0 = __builtin_amdgcn_mfma_f32_16x16x32_bf16(ha[0][kt], b, a0, 0, 0, 0);
            a1 = __builtin_amdgcn_mfma_f32_16x16x32_bf16(ha[1][kt], b, a1, 0, 0, 0);
        }
        const float bias = v_b[nt * 16 + l15];
#pragma unroll
        for (int r = 0; r < 4; ++r) {
            sV[wave][quad * 4 + r][nt * 16 + l15]      = f2bf(fmaxf(a0[r] + bias, 0.f));
            sV[wave][16 + quad * 4 + r][nt * 16 + l15] = f2bf(fmaxf(a1[r] + bias, 0.f));
        }
    }
    // per-wave LDS producer->consumer; no block barrier needed

    // DEC
    {
        floatx4 d0 = floatx4{0.f,0.f,0.f,0.f}, d1 = d0;
#pragma unroll
        for (int kt = 0; kt < 6; ++kt) {
            bf16x8 b = ld8(&wdec[kt * 512 + lane * 8]);
            bf16x8 a0 = (kt < 4) ? ha[0][kt] : ld8(&sV[wave][l15][(kt - 4) * 32 + quad * 8]);
            bf16x8 a1 = (kt < 4) ? ha[1][kt] : ld8(&sV[wave][16 + l15][(kt - 4) * 32 + quad * 8]);
            d0 = __builtin_amdgcn_mfma_f32_16x16x32_bf16(a0, b, d0, 0, 0, 0);
            d1 = __builtin_amdgcn_mfma_f32_16x16x32_bf16(a1, b, d1, 0, 0, 0);
        }
        if (l15 < 10) {
            const float bias = dec_b[l15];
#pragma unroll
            for (int r = 0; r < 4; ++r) {
                sO[wave][quad * 4 + r][l15]      = d0[r] + bias;
                sO[wave][16 + quad * 4 + r][l15] = d1[r] + bias;
            }
        }
#pragma unroll
        for (int j = 0; j < 5; ++j) {
            int idx = j * 64 + lane;          // 0..319
            int row = idx / 10, col = idx % 10;
            int grow = wrow0 + row;
            if (grow < SIZE)
                out[(size_t)grow * 10 + col] = sO[wave][row][col];
        }
    }
}

extern "C" void kernel_launch(void* const* d_in, const int* in_sizes, int n_in,
                              void* d_out, int out_size, void* d_ws, size_t ws_size,
                              hipStream_t stream) {
    const float* obs   = (const float*)d_in[0];
    const float* hid   = (const float*)d_in[1];
    const float* enc_w = (const float*)d_in[2];
    const float* enc_b = (const float*)d_in[3];
    const float* w_ih  = (const float*)d_in[4];
    const float* w_hh  = (const float*)d_in[5];
    const float* b_ih  = (const float*)d_in[6];
    const float* b_hh  = (const float*)d_in[7];
    // d_in[8..19]: dead code (bi-GRU / hard attention / q,k) — unused.
    const float* v_w   = (const float*)d_in[20];
    const float* v_b   = (const float*)d_in[21];
    const float* dec_w = (const float*)d_in[22];
    const float* dec_b = (const float*)d_in[23];
    unsigned short* wsw = (unsigned short*)d_ws;
    unsigned short* xws = wsw + X_WS;
    float* out   = (float*)d_out;
    float* out_h = out + (size_t)SIZE * 10;

    hipLaunchKernelGGL(cvt_weights, dim3((WS_TOTC + 255) / 256), dim3(256), 0, stream,
                       enc_w, w_ih, w_hh, v_w, dec_w, wsw);
    hipLaunchKernelGGL(pass1_enc, dim3(512), dim3(256), 0, stream,
                       obs, enc_b, wsw, xws);
    hipLaunchKernelGGL(pass2_gru, dim3(2048), dim3(256), 0, stream,
                       hid, b_ih, b_hh, wsw, xws, out_h);
    hipLaunchKernelGGL(pass3_vdec, dim3(512), dim3(256), 0, stream,
                       out_h, v_b, dec_b, wsw, out);
}